// Round 1
// baseline (69.149 us; speedup 1.0000x reference)
//
#include <hip/hip_runtime.h>

#define NN 16384
#define NT 1024
#define PER (NN / NT)

__global__ __launch_bounds__(NT) void dag_eval_kernel(
    const int* __restrict__ left,
    const int* __restrict__ right,
    const unsigned char* __restrict__ reroll_raw,
    int* __restrict__ out)
{
    __shared__ unsigned char reach[NN];
    __shared__ unsigned char hs[NN];
    __shared__ unsigned char hr[NN];
    __shared__ int changed;
    __shared__ int nzmask;
    __shared__ int cnt;

    const int tid = threadIdx.x;
    if (tid == 0) { nzmask = 0; cnt = 0; }
    __syncthreads();

    // ---- detect leaf_is_reroll layout (byte bool / int32 / float32) ----
    // Values are only 0/1 (or 0.0f/1.0f). Record which byte-lanes (idx&3)
    // hold nonzero bytes across the first 16384 bytes (safe for all layouts).
    int localmask = 0;
    #pragma unroll
    for (int k = 0; k < PER; ++k) {
        int idx = tid * PER + k;
        if (reroll_raw[idx]) localmask |= 1 << (idx & 3);
    }
    if (localmask) atomicOr(&nzmask, localmask);

    // ---- preload children into registers, init reach ----
    int lch[PER], rch[PER];
    #pragma unroll
    for (int k = 0; k < PER; ++k) {
        int i = tid + k * NT;
        lch[k] = left[i];
        rch[k] = right[i];
        reach[i] = (i == 0) ? 1 : 0;
    }
    __syncthreads();

    const int mask = nzmask;
    // layout: only lane0 (or none) nonzero -> int32; lanes 2/3 only -> f32;
    // otherwise raw byte bools.
    int layout;            // 0=int32, 1=float32, 2=byte
    if ((mask & ~1) == 0)      layout = 0;
    else if ((mask & 3) == 0)  layout = 1;
    else                       layout = 2;
    const int*   ri = (const int*)reroll_raw;
    const float* rf = (const float*)reroll_raw;

    // ---- init hs/hr with leaf-derived base flags ----
    #pragma unroll
    for (int k = 0; k < PER; ++k) {
        int i = tid + k * NT;
        bool bs = false, br = false;
        #pragma unroll
        for (int c2 = 0; c2 < 2; ++c2) {
            int c = c2 ? rch[k] : lch[k];
            if (c < 0) {
                int id = -c - 1;
                bool rr = (layout == 2) ? (reroll_raw[id] != 0)
                         : (layout == 1) ? (rf[id] != 0.0f)
                                         : (ri[id] != 0);
                bs |= !rr;
                br |= rr;
            }
        }
        hs[i] = bs ? 1 : 0;
        hr[i] = br ? 1 : 0;
    }
    __syncthreads();

    // ---- forward reachability fixpoint (push; monotone, races benign) ----
    for (;;) {
        __syncthreads();
        if (tid == 0) changed = 0;
        __syncthreads();
        bool ch = false;
        #pragma unroll
        for (int k = 0; k < PER; ++k) {
            int i = tid + k * NT;
            if (reach[i]) {
                int c = lch[k];
                if (c >= 0 && !reach[c]) { reach[c] = 1; ch = true; }
                c = rch[k];
                if (c >= 0 && !reach[c]) { reach[c] = 1; ch = true; }
            }
        }
        if (ch) changed = 1;
        __syncthreads();
        if (!changed) break;
    }

    // ---- subtree-flag fixpoint (pull; exact least fixpoint on DAG) ----
    for (;;) {
        __syncthreads();
        if (tid == 0) changed = 0;
        __syncthreads();
        bool ch = false;
        #pragma unroll
        for (int k = 0; k < PER; ++k) {
            int i = tid + k * NT;
            int c0 = lch[k], c1 = rch[k];
            if (!hs[i] && ((c0 >= 0 && hs[c0]) || (c1 >= 0 && hs[c1]))) {
                hs[i] = 1; ch = true;
            }
            if (!hr[i] && ((c0 >= 0 && hr[c0]) || (c1 >= 0 && hr[c1]))) {
                hr[i] = 1; ch = true;
            }
        }
        if (ch) changed = 1;
        __syncthreads();
        if (!changed) break;
    }

    // ---- count + write outputs (int32) ----
    int s = 0;
    #pragma unroll
    for (int k = 0; k < PER; ++k) s += reach[tid + k * NT];
    atomicAdd(&cnt, s);

    #pragma unroll
    for (int k = 0; k < PER; ++k) {
        int i = tid + k * NT;
        out[i]          = reach[i];
        out[NN + i]     = hs[i];
        out[2 * NN + i] = hr[i];
    }
    __syncthreads();
    if (tid == 0) out[3 * NN] = cnt;
}

extern "C" void kernel_launch(void* const* d_in, const int* in_sizes, int n_in,
                              void* d_out, int out_size, void* d_ws, size_t ws_size,
                              hipStream_t stream)
{
    // setup_inputs order: thresholds(0) rules(1) binary_ops(2) left(3) right(4)
    // leaf_is_reroll(5) leaf_mask_left(6) leaf_mask_right(7) leaf_mask_op(8)
    // leaf_score_cat(9)
    const int* left  = (const int*)d_in[3];
    const int* right = (const int*)d_in[4];
    const unsigned char* reroll = (const unsigned char*)d_in[5];
    int* out = (int*)d_out;
    dag_eval_kernel<<<1, NT, 0, stream>>>(left, right, reroll, out);
}

// Round 2
// 32.301 us; speedup vs baseline: 2.1408x; 2.1408x over previous
//
#include <hip/hip_runtime.h>

#define NN 16384
#define NT 1024
#define PER 16   // contiguous nodes per thread

__global__ __launch_bounds__(NT) void dag_eval_kernel(
    const int* __restrict__ left,
    const int* __restrict__ right,
    const unsigned char* __restrict__ reroll_raw,
    int* __restrict__ out)
{
    __shared__ unsigned char reach[NN];        // 16 KB, bytes 0/1
    __shared__ unsigned char state[NN + 16];   // hs|hr<<1 per node; state[NN]=0 dummy
    __shared__ int flags[2];
    __shared__ int nzmask;
    __shared__ int cnt;

    const int tid = threadIdx.x;
    const int b0  = tid * PER;

    if (tid == 0) { nzmask = 0; cnt = 0; flags[0] = 0; flags[1] = 0; }
    if (tid < 16) state[NN + tid] = 0;

    // ---- children, coalesced int4 loads (16B/lane) ----
    int lch[PER], rch[PER];
    {
        const int4* l4 = (const int4*)left;
        const int4* r4 = (const int4*)right;
        #pragma unroll
        for (int j = 0; j < PER / 4; ++j) {
            int4 a = l4[(b0 >> 2) + j];
            int4 b = r4[(b0 >> 2) + j];
            lch[4*j+0] = a.x; lch[4*j+1] = a.y; lch[4*j+2] = a.z; lch[4*j+3] = a.w;
            rch[4*j+0] = b.x; rch[4*j+1] = b.y; rch[4*j+2] = b.z; rch[4*j+3] = b.w;
        }
    }

    // ---- leaf_is_reroll layout detection (first 16 KB safe for all layouts) ----
    {
        uint4 v = ((const uint4*)reroll_raw)[tid];
        unsigned int t = v.x | v.y | v.z | v.w;
        unsigned int m = 0;
        if (t & 0x000000FFu) m |= 1u;
        if (t & 0x0000FF00u) m |= 2u;
        if (t & 0x00FF0000u) m |= 4u;
        if (t & 0xFF000000u) m |= 8u;
        if (m) atomicOr(&nzmask, (int)m);
    }

    *(uint4*)&reach[b0] = make_uint4(0u, 0u, 0u, 0u);
    __syncthreads();

    const int mask   = nzmask;
    const int layout = ((mask & ~1) == 0) ? 0 : (((mask & 3) == 0) ? 1 : 2); // int32/f32/byte
    const int*   ri = (const int*)reroll_raw;
    const float* rf = (const float*)reroll_raw;

    // ---- init backward state (leaf contributions), own copy in registers ----
    int sreg[PER];
    #pragma unroll
    for (int k = 0; k < PER; ++k) {
        int s = 0;
        int c = lch[k];
        if (c < 0) {
            int id = -c - 1;
            bool rr = (layout == 2) ? (reroll_raw[id] != 0)
                     : (layout == 1) ? (rf[id] != 0.0f)
                                     : (ri[id] != 0);
            s |= rr ? 2 : 1;
        }
        c = rch[k];
        if (c < 0) {
            int id = -c - 1;
            bool rr = (layout == 2) ? (reroll_raw[id] != 0)
                     : (layout == 1) ? (rf[id] != 0.0f)
                                     : (ri[id] != 0);
            s |= rr ? 2 : 1;
        }
        sreg[k] = s;
        state[b0 + k] = (unsigned char)s;
    }
    if (tid == 0) reach[0] = 1;
    __syncthreads();

    // ---- forward reachability: push-once fixpoint ----
    unsigned int pushed = 0, mm = 0;
    for (int s = 0; ; ++s) {
        uint4 rv = *(const uint4*)&reach[b0];            // one ds_read_b128
        // bytes are strictly 0/1 -> movemask via multiply
        mm  =  ((rv.x * 0x01020408u) >> 24) & 0xFu;
        mm |= (((rv.y * 0x01020408u) >> 24) & 0xFu) << 4;
        mm |= (((rv.z * 0x01020408u) >> 24) & 0xFu) << 8;
        mm |= (((rv.w * 0x01020408u) >> 24) & 0xFu) << 12;
        unsigned int newp = mm & ~pushed;
        pushed |= newp;
        const bool ch = (newp != 0u);
        while (newp) {
            int k = __builtin_ctz(newp);
            newp &= newp - 1u;
            int c = lch[k]; if (c >= 0) reach[c] = (unsigned char)1;
            c = rch[k];     if (c >= 0) reach[c] = (unsigned char)1;
        }
        int p = s & 1;
        if (ch) flags[p] = 1;
        __syncthreads();                                  // B1: sets visible
        int f = flags[p];
        if (tid == 0) flags[p ^ 1] = 0;                   // reset other parity
        __syncthreads();                                  // B2: reads done
        if (!f) break;
    }

    // ---- backward hs/hr fixpoint (pull, branchless gather, saturation skip) ----
    unsigned int unres = 0;
    #pragma unroll
    for (int k = 0; k < PER; ++k) if (sreg[k] != 3) unres |= 1u << k;

    for (int s = 0; ; ++s) {
        bool ch = false;
        if (unres) {
            int tl[PER], tr[PER];
            #pragma unroll
            for (int k = 0; k < PER; ++k) {
                bool act = (unres >> k) & 1u;
                int la = (act && lch[k] >= 0) ? lch[k] : NN;  // dummy reads 0
                int ra = (act && rch[k] >= 0) ? rch[k] : NN;
                tl[k] = state[la];
                tr[k] = state[ra];
            }
            #pragma unroll
            for (int k = 0; k < PER; ++k) {
                int ns = sreg[k] | tl[k] | tr[k];
                if (ns != sreg[k]) {
                    sreg[k] = ns;
                    state[b0 + k] = (unsigned char)ns;    // owner-only write
                    ch = true;
                    if (ns == 3) unres &= ~(1u << k);
                }
            }
        }
        int p = s & 1;
        if (ch) flags[p] = 1;
        __syncthreads();
        int f = flags[p];
        if (tid == 0) flags[p ^ 1] = 0;
        __syncthreads();
        if (!f) break;
    }

    // ---- count (wave shuffle reduce, one atomic per wave) ----
    int cc = __popc(mm);
    #pragma unroll
    for (int off = 32; off; off >>= 1) cc += __shfl_down(cc, off);
    if ((tid & 63) == 0) atomicAdd(&cnt, cc);

    // ---- outputs straight from registers, int4 stores ----
    int4* out4 = (int4*)out;
    #pragma unroll
    for (int j = 0; j < PER / 4; ++j) {
        int4 a, h, r;
        a.x = (mm >> (4*j+0)) & 1; a.y = (mm >> (4*j+1)) & 1;
        a.z = (mm >> (4*j+2)) & 1; a.w = (mm >> (4*j+3)) & 1;
        h.x =  sreg[4*j+0] & 1;       h.y =  sreg[4*j+1] & 1;
        h.z =  sreg[4*j+2] & 1;       h.w =  sreg[4*j+3] & 1;
        r.x = (sreg[4*j+0] >> 1) & 1; r.y = (sreg[4*j+1] >> 1) & 1;
        r.z = (sreg[4*j+2] >> 1) & 1; r.w = (sreg[4*j+3] >> 1) & 1;
        out4[(b0 >> 2) + j]              = a;
        out4[((NN + b0) >> 2) + j]       = h;
        out4[((2 * NN + b0) >> 2) + j]   = r;
    }
    __syncthreads();
    if (tid == 0) out[3 * NN] = cnt;
}

extern "C" void kernel_launch(void* const* d_in, const int* in_sizes, int n_in,
                              void* d_out, int out_size, void* d_ws, size_t ws_size,
                              hipStream_t stream)
{
    const int* left  = (const int*)d_in[3];
    const int* right = (const int*)d_in[4];
    const unsigned char* reroll = (const unsigned char*)d_in[5];
    int* out = (int*)d_out;
    dag_eval_kernel<<<1, NT, 0, stream>>>(left, right, reroll, out);
}